// Round 1
// baseline (493.592 us; speedup 1.0000x reference)
//
#include <hip/hip_runtime.h>

// Fastfood transform: out = (1/sqrt(d)) * S * H( G * P( H( B * x ) ) )
// d = 1024, rows = 2*2048*16 = 65536, fp32 in/out.
//
// One wave (64 lanes) per row; lane owns 16 consecutive elements.
// WHT-1024 = 4 register stages (h=1,2,4,8) + 6 shuffle stages (h=16..512,
// lane xor 1..32). Only LDS use is the permutation gather (wave-private
// 4 KB slice). B/G/S/P hoisted to registers, reused across 8 rows/wave.

constexpr int D = 1024;
constexpr int THREADS = 256;
constexpr int WAVES_PER_BLOCK = 4;
constexpr int ROWS_PER_WAVE = 8;
constexpr int ROWS_PER_BLOCK = WAVES_PER_BLOCK * ROWS_PER_WAVE; // 32

__device__ __forceinline__ void fwht1024(float v[16], int lane) {
    // stages h = 1,2,4,8 : register-local (lane owns elements 16L..16L+15)
    #pragma unroll
    for (int h = 1; h <= 8; h <<= 1) {
        #pragma unroll
        for (int j = 0; j < 16; ++j) {
            if ((j & h) == 0) {
                float a = v[j], c = v[j ^ h];
                v[j]     = a + c;
                v[j ^ h] = a - c;
            }
        }
    }
    // stages h = 16,32,64,128,256,512 : cross-lane via shfl_xor(1..32)
    #pragma unroll
    for (int m = 1; m <= 32; m <<= 1) {
        float sgn = (lane & m) ? -1.0f : 1.0f;
        #pragma unroll
        for (int j = 0; j < 16; ++j) {
            float partner = __shfl_xor(v[j], m, 64);
            // low lane:  v + partner ; high lane: partner - v
            v[j] = fmaf(sgn, v[j], partner);
        }
    }
}

__global__ __launch_bounds__(THREADS) void fastfood_kernel(
    const float* __restrict__ x,
    const float* __restrict__ Bv,
    const float* __restrict__ Gv,
    const float* __restrict__ Sv,
    const int*   __restrict__ Pv,
    float* __restrict__ out)
{
    __shared__ float lds[WAVES_PER_BLOCK * D]; // 16 KB, one 4 KB slice per wave

    const int lane  = threadIdx.x & 63;
    const int wave  = threadIdx.x >> 6;
    float* slice    = lds + wave * D;
    const int ebase = lane << 4; // first of this lane's 16 elements

    // Row-invariant params into registers (L1-cached loads, once per wave).
    float b[16], g[16], s[16];
    int   p[16];
    #pragma unroll
    for (int q = 0; q < 4; ++q) {
        float4 tb = reinterpret_cast<const float4*>(Bv + ebase)[q];
        float4 tg = reinterpret_cast<const float4*>(Gv + ebase)[q];
        float4 ts = reinterpret_cast<const float4*>(Sv + ebase)[q];
        int4   tp = reinterpret_cast<const int4 *>(Pv + ebase)[q];
        const float inv = 1.0f / 32.0f; // 1/sqrt(1024), SCALE=1
        b[4*q+0]=tb.x; b[4*q+1]=tb.y; b[4*q+2]=tb.z; b[4*q+3]=tb.w;
        g[4*q+0]=tg.x; g[4*q+1]=tg.y; g[4*q+2]=tg.z; g[4*q+3]=tg.w;
        s[4*q+0]=ts.x*inv; s[4*q+1]=ts.y*inv; s[4*q+2]=ts.z*inv; s[4*q+3]=ts.w*inv;
        p[4*q+0]=tp.x; p[4*q+1]=tp.y; p[4*q+2]=tp.z; p[4*q+3]=tp.w;
    }

    for (int i = 0; i < ROWS_PER_WAVE; ++i) {
        const int row = blockIdx.x * ROWS_PER_BLOCK + i * WAVES_PER_BLOCK + wave;
        const float* xr = x + (size_t)row * D;

        float v[16];
        #pragma unroll
        for (int q = 0; q < 4; ++q) {
            float4 t = reinterpret_cast<const float4*>(xr + ebase)[q];
            v[4*q+0] = t.x * b[4*q+0];
            v[4*q+1] = t.y * b[4*q+1];
            v[4*q+2] = t.z * b[4*q+2];
            v[4*q+3] = t.w * b[4*q+3];
        }

        fwht1024(v, lane); // v = H(Bx), consecutive layout

        // Stage row in LDS for the permutation gather.
        #pragma unroll
        for (int q = 0; q < 4; ++q) {
            reinterpret_cast<float4*>(slice + ebase)[q] =
                make_float4(v[4*q+0], v[4*q+1], v[4*q+2], v[4*q+3]);
        }
        __syncthreads(); // orders intra-wave LDS write->gather-read (slices are
                         // wave-private; all waves hit the same trip count)

        #pragma unroll
        for (int j = 0; j < 16; ++j)
            v[j] = slice[p[j]] * g[j]; // GPHBx

        fwht1024(v, lane); // v = H(GPHBx)

        float* outr = out + (size_t)row * D;
        #pragma unroll
        for (int q = 0; q < 4; ++q) {
            float4 t;
            t.x = v[4*q+0] * s[4*q+0];
            t.y = v[4*q+1] * s[4*q+1];
            t.z = v[4*q+2] * s[4*q+2];
            t.w = v[4*q+3] * s[4*q+3];
            reinterpret_cast<float4*>(outr + ebase)[q] = t;
        }
        __syncthreads(); // WAR: next iteration's LDS writes vs this gather's reads
    }
}

extern "C" void kernel_launch(void* const* d_in, const int* in_sizes, int n_in,
                              void* d_out, int out_size, void* d_ws, size_t ws_size,
                              hipStream_t stream) {
    const float* x  = (const float*)d_in[0];
    const float* Bv = (const float*)d_in[1];
    const float* Gv = (const float*)d_in[2];
    const float* Sv = (const float*)d_in[3];
    const int*   Pv = (const int*)d_in[4];
    float* out = (float*)d_out;

    const int nrows  = in_sizes[0] / D;           // 65536
    const int blocks = nrows / ROWS_PER_BLOCK;    // 2048 (divides exactly)
    fastfood_kernel<<<blocks, THREADS, 0, stream>>>(x, Bv, Gv, Sv, Pv, out);
}

// Round 2
// 465.186 us; speedup vs baseline: 1.0611x; 1.0611x over previous
//
#include <hip/hip_runtime.h>

// Fastfood transform: out = (1/sqrt(d)) * S * H( G * P( H( B * x ) ) )
// d = 1024, rows = 65536, fp32.
//
// One wave per row; lane owns 16 consecutive elements (element n = 16*lane + j).
// WHT-1024 = 4 register stages (element bits 0-3) + 6 lane stages (bits 4-9).
// Lane stages run entirely on the VALU (DPP + gfx950 permlane*_swap), keeping
// the DS pipe free for the single permutation-gather round trip. LDS slices
// are wave-private and same-wave DS ops execute in order -> no barriers.

constexpr int D = 1024;
constexpr int THREADS = 256;
constexpr int WAVES_PER_BLOCK = 4;
constexpr int ROWS_PER_WAVE = 8;
constexpr int ROWS_PER_BLOCK = WAVES_PER_BLOCK * ROWS_PER_WAVE; // 32

#if defined(__has_builtin)
#if __has_builtin(__builtin_amdgcn_permlane16_swap) && __has_builtin(__builtin_amdgcn_permlane32_swap)
#define HAS_PLSWAP 1
#endif
#endif

// DPP-based lane permute (VALU, not DS). CTRL: quad_perm / row_* encodings.
template <int CTRL>
__device__ __forceinline__ float dppmov(float x) {
    return __int_as_float(
        __builtin_amdgcn_update_dpp(0, __float_as_int(x), CTRL, 0xF, 0xF, false));
}

// Butterfly helper: new = partner + sgn*own, sgn = -1 on high-side lanes.
__device__ __forceinline__ void fwht1024(float v[16], float sg1, float sg2,
                                         float sg4, float sg8, float sg16,
                                         float sg32) {
    // Register stages h = 1,2,4,8 (element bits 0-3).
    #pragma unroll
    for (int h = 1; h <= 8; h <<= 1) {
        #pragma unroll
        for (int j = 0; j < 16; ++j) {
            if ((j & h) == 0) {
                float a = v[j], c = v[j ^ h];
                v[j]     = a + c;
                v[j ^ h] = a - c;
            }
        }
    }
    // Lane mask 1: quad_perm [1,0,3,2]
    #pragma unroll
    for (int j = 0; j < 16; ++j) {
        float p = dppmov<0xB1>(v[j]);
        v[j] = fmaf(sg1, v[j], p);
    }
    // Lane mask 2: quad_perm [2,3,0,1]
    #pragma unroll
    for (int j = 0; j < 16; ++j) {
        float p = dppmov<0x4E>(v[j]);
        v[j] = fmaf(sg2, v[j], p);
    }
    // Lane mask 4: xor4 = row_half_mirror(xor7) o quad_perm[3,2,1,0](xor3)
    #pragma unroll
    for (int j = 0; j < 16; ++j) {
        float p = dppmov<0x141>(dppmov<0x1B>(v[j]));
        v[j] = fmaf(sg4, v[j], p);
    }
    // Lane mask 8: row_ror:8 (rotate by 8 in group of 16 == xor 8)
    #pragma unroll
    for (int j = 0; j < 16; ++j) {
        float p = dppmov<0x128>(v[j]);
        v[j] = fmaf(sg8, v[j], p);
    }
#ifdef HAS_PLSWAP
    // Lane mask 16: v_permlane16_swap_b32(v, v) -> r[0]=even-row vals, r[1]=odd.
    #pragma unroll
    for (int j = 0; j < 16; ++j) {
        auto r = __builtin_amdgcn_permlane16_swap(__float_as_uint(v[j]),
                                                  __float_as_uint(v[j]), false, false);
        v[j] = fmaf(sg16, __uint_as_float(r[1]), __uint_as_float(r[0]));
    }
    // Lane mask 32: v_permlane32_swap_b32.
    #pragma unroll
    for (int j = 0; j < 16; ++j) {
        auto r = __builtin_amdgcn_permlane32_swap(__float_as_uint(v[j]),
                                                  __float_as_uint(v[j]), false, false);
        v[j] = fmaf(sg32, __uint_as_float(r[1]), __uint_as_float(r[0]));
    }
#else
    #pragma unroll
    for (int j = 0; j < 16; ++j) {
        float p = __shfl_xor(v[j], 16, 64);
        v[j] = fmaf(sg16, v[j], p);
    }
    #pragma unroll
    for (int j = 0; j < 16; ++j) {
        float p = __shfl_xor(v[j], 32, 64);
        v[j] = fmaf(sg32, v[j], p);
    }
#endif
}

__global__ __launch_bounds__(THREADS) void fastfood_kernel(
    const float* __restrict__ x,
    const float* __restrict__ Bv,
    const float* __restrict__ Gv,
    const float* __restrict__ Sv,
    const int*   __restrict__ Pv,
    float* __restrict__ out)
{
    __shared__ float lds[WAVES_PER_BLOCK * D]; // 16 KB, one 4 KB slice per wave

    const int lane  = threadIdx.x & 63;
    const int wave  = threadIdx.x >> 6;
    float* slice    = lds + wave * D;
    const int ebase = lane << 4;

    const float sg1  = (lane & 1)  ? -1.0f : 1.0f;
    const float sg2  = (lane & 2)  ? -1.0f : 1.0f;
    const float sg4  = (lane & 4)  ? -1.0f : 1.0f;
    const float sg8  = (lane & 8)  ? -1.0f : 1.0f;
    const float sg16 = (lane & 16) ? -1.0f : 1.0f;
    const float sg32 = (lane & 32) ? -1.0f : 1.0f;

    // Row-invariant params into registers (once per wave).
    float b[16], g[16], s[16];
    int   p[16];
    #pragma unroll
    for (int q = 0; q < 4; ++q) {
        float4 tb = reinterpret_cast<const float4*>(Bv + ebase)[q];
        float4 tg = reinterpret_cast<const float4*>(Gv + ebase)[q];
        float4 ts = reinterpret_cast<const float4*>(Sv + ebase)[q];
        int4   tp = reinterpret_cast<const int4 *>(Pv + ebase)[q];
        const float inv = 1.0f / 32.0f; // 1/sqrt(1024), SCALE=1
        b[4*q+0]=tb.x; b[4*q+1]=tb.y; b[4*q+2]=tb.z; b[4*q+3]=tb.w;
        g[4*q+0]=tg.x; g[4*q+1]=tg.y; g[4*q+2]=tg.z; g[4*q+3]=tg.w;
        s[4*q+0]=ts.x*inv; s[4*q+1]=ts.y*inv; s[4*q+2]=ts.z*inv; s[4*q+3]=ts.w*inv;
        p[4*q+0]=tp.x; p[4*q+1]=tp.y; p[4*q+2]=tp.z; p[4*q+3]=tp.w;
    }

    for (int i = 0; i < ROWS_PER_WAVE; ++i) {
        const int row = blockIdx.x * ROWS_PER_BLOCK + i * WAVES_PER_BLOCK + wave;
        const float* xr = x + (size_t)row * D;

        float v[16];
        #pragma unroll
        for (int q = 0; q < 4; ++q) {
            float4 t = reinterpret_cast<const float4*>(xr + ebase)[q];
            v[4*q+0] = t.x * b[4*q+0];
            v[4*q+1] = t.y * b[4*q+1];
            v[4*q+2] = t.z * b[4*q+2];
            v[4*q+3] = t.w * b[4*q+3];
        }

        fwht1024(v, sg1, sg2, sg4, sg8, sg16, sg32); // H(Bx)

        // Permutation gather through wave-private LDS (same-wave DS ops are
        // in-order: no barrier needed).
        #pragma unroll
        for (int q = 0; q < 4; ++q) {
            reinterpret_cast<float4*>(slice + ebase)[q] =
                make_float4(v[4*q+0], v[4*q+1], v[4*q+2], v[4*q+3]);
        }
        #pragma unroll
        for (int j = 0; j < 16; ++j)
            v[j] = slice[p[j]] * g[j]; // G * P(HBx)

        fwht1024(v, sg1, sg2, sg4, sg8, sg16, sg32); // H(GPHBx)

        float* outr = out + (size_t)row * D;
        #pragma unroll
        for (int q = 0; q < 4; ++q) {
            float4 t;
            t.x = v[4*q+0] * s[4*q+0];
            t.y = v[4*q+1] * s[4*q+1];
            t.z = v[4*q+2] * s[4*q+2];
            t.w = v[4*q+3] * s[4*q+3];
            reinterpret_cast<float4*>(outr + ebase)[q] = t;
        }
    }
}

extern "C" void kernel_launch(void* const* d_in, const int* in_sizes, int n_in,
                              void* d_out, int out_size, void* d_ws, size_t ws_size,
                              hipStream_t stream) {
    const float* x  = (const float*)d_in[0];
    const float* Bv = (const float*)d_in[1];
    const float* Gv = (const float*)d_in[2];
    const float* Sv = (const float*)d_in[3];
    const int*   Pv = (const int*)d_in[4];
    float* out = (float*)d_out;

    const int nrows  = in_sizes[0] / D;           // 65536
    const int blocks = nrows / ROWS_PER_BLOCK;    // 2048
    fastfood_kernel<<<blocks, THREADS, 0, stream>>>(x, Bv, Gv, Sv, Pv, out);
}